// Round 7
// baseline (61.764 us; speedup 1.0000x reference)
//
#include <hip/hip_runtime.h>
#include <math.h>

#define BATCH 512
#define HH 224
#define WW 224
#define NPIX (HH * WW)
#define NL 3
#define EPSV 1e-5f
#define STRIPS 8
#define RPB (HH / STRIPS)     // 28 output rows per block
#define LROWS (RPB + 2)       // 30 staged input rows (with halo)
#define LSTR 232              // LDS row stride in floats: 4 pad + 224 + 4 pad
#define NCHUNK (LROWS * (WW / 4))   // 30*56 = 1680 float4 chunks per block

// ---------------- Kernel 1: conv3x3(1->4) + relu + partial sums ----------------
// One block = one 28-row strip. Phase 1: stage 30 rows into LDS (7 independent
// float4 loads/thread, zero-filled halo, padded rows). Phase 2: pure LDS+VALU —
// per window row 3 aligned ds_read_b128 (stride-16B, conflict-free), 36 FMA/px.
// No __shfl, no exec-mask churn, loads fully decoupled from compute.
// R5 lesson: no min-waves launch bound (spill). R6 lesson: compiler won't keep
// a deep global-load pipeline in regs; LDS staging forces the decoupling.
__global__ __launch_bounds__(256) void conv_pool_k(
    const float* __restrict__ x, const float* __restrict__ cw,
    float* __restrict__ part)
{
  __shared__ float lds[LROWS * LSTR];   // 27840 B
  __shared__ float pl[4][4];

  const int blk = blockIdx.x;
  const int b = blk >> 3;          // image
  const int s = blk & 7;           // strip
  const int tid = threadIdx.x;
  const float* __restrict__ img = x + (size_t)b * NPIX;
  const int row0g = s * RPB - 1;   // global row of LDS row 0

  // ---- Phase 1: stage strip (+halo) into LDS ----
  // zero the left/right pads (4 words each side per row)
  if (tid < LROWS * 8) {
    const int r = tid >> 3, o = tid & 7;
    lds[r * LSTR + (o < 4 ? o : 224 + o)] = 0.f;
  }
#pragma unroll
  for (int k = 0; k < 7; ++k) {
    const int id = tid + k * 256;
    if (id < NCHUNK) {
      const int r = id / 56;        // LDS row 0..29
      const int c4 = id % 56;       // float4 chunk within row
      const int grow = row0g + r;
      float4 v = make_float4(0.f, 0.f, 0.f, 0.f);
      if ((unsigned)grow < (unsigned)HH)
        v = *reinterpret_cast<const float4*>(img + (size_t)grow * WW + c4 * 4);
      *reinterpret_cast<float4*>(&lds[r * LSTR + 4 + c4 * 4]) = v;
    }
  }
  __syncthreads();

  // ---- Phase 2: compute from LDS ----
  // 4x9 weights: uniform address -> scalar loads
  float K[4][9];
#pragma unroll
  for (int o = 0; o < 4; ++o)
#pragma unroll
    for (int k = 0; k < 9; ++k) K[o][k] = cw[o * 9 + k];

  const int wv = tid >> 6;         // wave 0..3, owns 7 output rows
  const int lane = tid & 63;
  const int c0 = (lane < 56 ? lane : 55) * 4;  // clamped: lanes 56..63 dup lane55
  const int jbase = wv * 7;        // strip-local first output row

  // window row r (LDS row index) -> 6 floats [c0-1 .. c0+4]
  // word for col v is r*LSTR + 4 + v; the three b128 are 16B-aligned, stride-16B
  auto ldwin = [&](int r, float (&R)[6]) {
    const float* rowp = &lds[r * LSTR + c0];
    const float4 L = *reinterpret_cast<const float4*>(rowp);      // cols c0-4..c0-1
    const float4 M = *reinterpret_cast<const float4*>(rowp + 4);  // cols c0..c0+3
    const float4 Rr = *reinterpret_cast<const float4*>(rowp + 8); // cols c0+4..c0+7
    R[0] = L.w; R[1] = M.x; R[2] = M.y; R[3] = M.z; R[4] = M.w; R[5] = Rr.x;
  };

  float E[3][6];
  ldwin(jbase, E[0]);          // input row (strip-local j=0 window top)
  ldwin(jbase + 1, E[1]);

  float acc0 = 0.f, acc1 = 0.f, acc2 = 0.f, acc3 = 0.f;

#pragma unroll
  for (int i = 0; i < 7; ++i) {    // 7 output rows per wave
    float (&A)[6] = E[i % 3];
    float (&B)[6] = E[(i + 1) % 3];
    float (&C)[6] = E[(i + 2) % 3];
    ldwin(jbase + i + 2, C);

#pragma unroll
    for (int p = 0; p < 4; ++p) {
      const float a0 = A[p], a1 = A[p + 1], a2 = A[p + 2];
      const float b0 = B[p], b1 = B[p + 1], b2 = B[p + 2];
      const float c0f = C[p], c1f = C[p + 1], c2f = C[p + 2];
      float t0 = fmaf(a0, K[0][0], fmaf(a1, K[0][1], fmaf(a2, K[0][2],
                 fmaf(b0, K[0][3], fmaf(b1, K[0][4], fmaf(b2, K[0][5],
                 fmaf(c0f, K[0][6], fmaf(c1f, K[0][7], c2f * K[0][8]))))))));
      float t1 = fmaf(a0, K[1][0], fmaf(a1, K[1][1], fmaf(a2, K[1][2],
                 fmaf(b0, K[1][3], fmaf(b1, K[1][4], fmaf(b2, K[1][5],
                 fmaf(c0f, K[1][6], fmaf(c1f, K[1][7], c2f * K[1][8]))))))));
      float t2 = fmaf(a0, K[2][0], fmaf(a1, K[2][1], fmaf(a2, K[2][2],
                 fmaf(b0, K[2][3], fmaf(b1, K[2][4], fmaf(b2, K[2][5],
                 fmaf(c0f, K[2][6], fmaf(c1f, K[2][7], c2f * K[2][8]))))))));
      float t3 = fmaf(a0, K[3][0], fmaf(a1, K[3][1], fmaf(a2, K[3][2],
                 fmaf(b0, K[3][3], fmaf(b1, K[3][4], fmaf(b2, K[3][5],
                 fmaf(c0f, K[3][6], fmaf(c1f, K[3][7], c2f * K[3][8]))))))));
      acc0 += fmaxf(t0, 0.f);
      acc1 += fmaxf(t1, 0.f);
      acc2 += fmaxf(t2, 0.f);
      acc3 += fmaxf(t3, 0.f);
    }
  }

  // lanes 56..63 duplicated lane55's columns: zero before reduction (R2 lesson)
  if (lane >= 56) { acc0 = 0.f; acc1 = 0.f; acc2 = 0.f; acc3 = 0.f; }

#pragma unroll
  for (int off = 32; off > 0; off >>= 1) {
    acc0 += __shfl_down(acc0, off);
    acc1 += __shfl_down(acc1, off);
    acc2 += __shfl_down(acc2, off);
    acc3 += __shfl_down(acc3, off);
  }
  if (lane == 0) {
    pl[wv][0] = acc0; pl[wv][1] = acc1; pl[wv][2] = acc2; pl[wv][3] = acc3;
  }
  __syncthreads();
  if (tid < 4) {
    float ssum = 0.f;
#pragma unroll
    for (int w = 0; w < 4; ++w) ssum += pl[w][tid];
    part[blk * 4 + tid] = ssum;
  }
}

// ---------------- Kernel 2: 4-qubit circuit + BatchNorm ----------------
template <int M>
__device__ __forceinline__ void ry_g(float (&sr)[16], float (&si)[16], float th) {
  float s, c;
  sincosf(0.5f * th, &s, &c);
#pragma unroll
  for (int i = 0; i < 16; ++i) {
    if (!(i & M)) {
      const int j = i | M;
      float r0 = sr[i], q0 = si[i], r1 = sr[j], q1 = si[j];
      sr[i] = c * r0 - s * r1;  si[i] = c * q0 - s * q1;
      sr[j] = s * r0 + c * r1;  si[j] = s * q0 + c * q1;
    }
  }
}

template <int M>
__device__ __forceinline__ void rz_g(float (&sr)[16], float (&si)[16], float th) {
  float s, c;
  sincosf(0.5f * th, &s, &c);
#pragma unroll
  for (int i = 0; i < 16; ++i) {
    float a = sr[i], q = si[i];
    if (i & M) { sr[i] = a * c - q * s;  si[i] = q * c + a * s; }
    else       { sr[i] = a * c + q * s;  si[i] = q * c - a * s; }
  }
}

template <int MC, int MT>
__device__ __forceinline__ void cnot_g(float (&sr)[16], float (&si)[16]) {
#pragma unroll
  for (int i = 0; i < 16; ++i) {
    if ((i & MC) && !(i & MT)) {
      const int j = i | MT;
      float tr = sr[i]; sr[i] = sr[j]; sr[j] = tr;
      float ti = si[i]; si[i] = si[j]; si[j] = ti;
    }
  }
}

__global__ __launch_bounds__(512) void circuit_bn_k(
    const float* __restrict__ part, const float* __restrict__ params,
    const float* __restrict__ gamma, const float* __restrict__ beta,
    float* __restrict__ out)
{
  const int b = threadIdx.x;

  float f[4];
#pragma unroll
  for (int w = 0; w < 4; ++w) {
    float ssum = 0.f;
#pragma unroll
    for (int s8 = 0; s8 < STRIPS; ++s8) ssum += part[(b * STRIPS + s8) * 4 + w];
    f[w] = ssum * (1.0f / NPIX);
  }

  float sr[16], si[16];
#pragma unroll
  for (int i = 0; i < 16; ++i) { sr[i] = 0.f; si[i] = 0.f; }
  sr[0] = 1.f;

  ry_g<8>(sr, si, f[0]);
  ry_g<4>(sr, si, f[1]);
  ry_g<2>(sr, si, f[2]);
  ry_g<1>(sr, si, f[3]);

  for (int l = 0; l < NL; ++l) {
    const float* pp = params + l * 8;
    ry_g<8>(sr, si, pp[0]); rz_g<8>(sr, si, pp[1]);
    ry_g<4>(sr, si, pp[2]); rz_g<4>(sr, si, pp[3]);
    ry_g<2>(sr, si, pp[4]); rz_g<2>(sr, si, pp[5]);
    ry_g<1>(sr, si, pp[6]); rz_g<1>(sr, si, pp[7]);
    cnot_g<8, 4>(sr, si);
    cnot_g<4, 2>(sr, si);
    cnot_g<2, 1>(sr, si);
  }

  float p[16];
#pragma unroll
  for (int i = 0; i < 16; ++i) p[i] = sr[i] * sr[i] + si[i] * si[i];

  float ev[4];
#pragma unroll
  for (int w = 0; w < 4; ++w) {
    const int m = 8 >> w;
    float ssum = 0.f;
#pragma unroll
    for (int i = 0; i < 16; ++i) ssum += (i & m) ? -p[i] : p[i];
    ev[w] = ssum;
  }

  float sum[4], sq[4];
#pragma unroll
  for (int w = 0; w < 4; ++w) { sum[w] = ev[w]; sq[w] = ev[w] * ev[w]; }
#pragma unroll
  for (int off = 32; off > 0; off >>= 1) {
#pragma unroll
    for (int w = 0; w < 4; ++w) {
      sum[w] += __shfl_down(sum[w], off);
      sq[w]  += __shfl_down(sq[w],  off);
    }
  }
  __shared__ float psum[8][4], psq[8][4];
  __shared__ float mean_s[4], rstd_s[4];
  const int wave = b >> 6;
  const int lane = b & 63;
  if (lane == 0) {
#pragma unroll
    for (int w = 0; w < 4; ++w) { psum[wave][w] = sum[w]; psq[wave][w] = sq[w]; }
  }
  __syncthreads();
  if (b < 4) {
    float ssum = 0.f, q = 0.f;
#pragma unroll
    for (int wv = 0; wv < 8; ++wv) { ssum += psum[wv][b]; q += psq[wv][b]; }
    const float m = ssum * (1.0f / BATCH);
    const float v = q * (1.0f / BATCH) - m * m;
    mean_s[b] = m;
    rstd_s[b] = rsqrtf(v + EPSV);
  }
  __syncthreads();
#pragma unroll
  for (int w = 0; w < 4; ++w) {
    out[b * 4 + w] = gamma[w] * (ev[w] - mean_s[w]) * rstd_s[w] + beta[w];
  }
}

extern "C" void kernel_launch(void* const* d_in, const int* in_sizes, int n_in,
                              void* d_out, int out_size, void* d_ws, size_t ws_size,
                              hipStream_t stream) {
  const float* x      = (const float*)d_in[0];
  const float* cw     = (const float*)d_in[1];
  const float* params = (const float*)d_in[2];
  const float* gamma  = (const float*)d_in[3];
  const float* beta   = (const float*)d_in[4];
  float* out  = (float*)d_out;
  float* part = (float*)d_ws;   // 512*8*4 f32 partial sums

  const int B = in_sizes[0] / NPIX;  // 512

  conv_pool_k<<<B * STRIPS, 256, 0, stream>>>(x, cw, part);
  circuit_bn_k<<<1, 512, 0, stream>>>(part, params, gamma, beta, out);
}

// Round 8
// 54.793 us; speedup vs baseline: 1.1272x; 1.1272x over previous
//
#include <hip/hip_runtime.h>
#include <math.h>

#define BATCH 512
#define HH 224
#define WW 224
#define NPIX (HH * WW)
#define NL 3
#define EPSV 1e-5f
#define GROUPS 14            // row-groups (blocks) per image; block covers 16 rows
#define ROWS_PER_WAVE 4      // wave covers 4 output rows

// ---------------- Kernel 1: conv3x3(1->4) + relu + partial sums ----------------
// Grid: 512 images * 14 groups. Block: 256 threads = 4 waves; wave owns 4 output
// rows x 224 cols; lane owns 4 cols (lanes 0..55 active, 56..63 clamped+zeroed).
// ALL 6 input rows are loaded up-front as unconditional float4 loads (row index
// clamped to [0,223]; logically-OOB rows zeroed AFTER the load by a wave-uniform
// branch) -> the compiler cannot sink them; one vmcnt batch per wave hides under
// ~1400 VALU cycles, x8 waves/SIMD.
// R5 lesson: no min-waves launch bound (spill). R6 lesson: guarded per-iter
// loads get sunk next to use -> no pipelining. R7 lesson: LDS round-trip costs
// occupancy + bank conflicts without fixing the latency chain.
__global__ __launch_bounds__(256) void conv_pool_k(
    const float* __restrict__ x, const float* __restrict__ cw,
    float* __restrict__ part)
{
  const int blk = blockIdx.x;
  const int b = blk / GROUPS;      // image
  const int g = blk % GROUPS;      // row-group
  const int tid = threadIdx.x;
  const int wv = __builtin_amdgcn_readfirstlane(tid >> 6);  // SGPR wave id
  const int lane = tid & 63;
  const int r0 = g * 16 + wv * ROWS_PER_WAVE;   // first output row (SGPR)
  const int colc = (lane < 56 ? lane : 55) * 4; // clamped col
  const float* __restrict__ img = x + (size_t)b * NPIX;

  // 4x9 weights: uniform address -> scalar loads -> SGPRs
  float K[4][9];
#pragma unroll
  for (int o = 0; o < 4; ++o)
#pragma unroll
    for (int k = 0; k < 9; ++k) K[o][k] = cw[o * 9 + k];

  // ---- load ALL 6 input rows up front (unconditional, clamped addresses) ----
  float4 v[6];
#pragma unroll
  for (int k = 0; k < 6; ++k) {
    int rr = r0 - 1 + k;                       // wave-uniform
    int rc = rr < 0 ? 0 : (rr > HH - 1 ? HH - 1 : rr);
    v[k] = *reinterpret_cast<const float4*>(img + (size_t)rc * WW + colc);
  }
  // zero logically-OOB rows (wave-uniform branch; only group 0 / group 13 hit)
#pragma unroll
  for (int k = 0; k < 6; ++k) {
    int rr = r0 - 1 + k;
    if (rr < 0 || rr > HH - 1) v[k] = make_float4(0.f, 0.f, 0.f, 0.f);
  }

  // expand float4 into [left, x, y, z, w, right] via cross-lane shfl
  auto expand = [&](const float4& t, float (&R)[6]) {
    float lft = __shfl_up(t.w, 1);
    R[0] = (lane == 0) ? 0.f : lft;       // image left edge
    float rgt = __shfl_down(t.x, 1);
    R[5] = (lane == 55) ? 0.f : rgt;      // image right edge (lane56 dups lane55)
    R[1] = t.x; R[2] = t.y; R[3] = t.z; R[4] = t.w;
  };

  float E[3][6];
  expand(v[0], E[0]);
  expand(v[1], E[1]);

  float acc0 = 0.f, acc1 = 0.f, acc2 = 0.f, acc3 = 0.f;

#pragma unroll
  for (int i = 0; i < ROWS_PER_WAVE; ++i) {   // 4 output rows
    float (&A)[6] = E[i % 3];
    float (&B)[6] = E[(i + 1) % 3];
    float (&C)[6] = E[(i + 2) % 3];
    expand(v[i + 2], C);

#pragma unroll
    for (int p = 0; p < 4; ++p) {
      const float a0 = A[p], a1 = A[p + 1], a2 = A[p + 2];
      const float b0 = B[p], b1 = B[p + 1], b2 = B[p + 2];
      const float c0 = C[p], c1 = C[p + 1], c2 = C[p + 2];
      float t0 = fmaf(a0, K[0][0], fmaf(a1, K[0][1], fmaf(a2, K[0][2],
                 fmaf(b0, K[0][3], fmaf(b1, K[0][4], fmaf(b2, K[0][5],
                 fmaf(c0, K[0][6], fmaf(c1, K[0][7], c2 * K[0][8]))))))));
      float t1 = fmaf(a0, K[1][0], fmaf(a1, K[1][1], fmaf(a2, K[1][2],
                 fmaf(b0, K[1][3], fmaf(b1, K[1][4], fmaf(b2, K[1][5],
                 fmaf(c0, K[1][6], fmaf(c1, K[1][7], c2 * K[1][8]))))))));
      float t2 = fmaf(a0, K[2][0], fmaf(a1, K[2][1], fmaf(a2, K[2][2],
                 fmaf(b0, K[2][3], fmaf(b1, K[2][4], fmaf(b2, K[2][5],
                 fmaf(c0, K[2][6], fmaf(c1, K[2][7], c2 * K[2][8]))))))));
      float t3 = fmaf(a0, K[3][0], fmaf(a1, K[3][1], fmaf(a2, K[3][2],
                 fmaf(b0, K[3][3], fmaf(b1, K[3][4], fmaf(b2, K[3][5],
                 fmaf(c0, K[3][6], fmaf(c1, K[3][7], c2 * K[3][8]))))))));
      acc0 += fmaxf(t0, 0.f);
      acc1 += fmaxf(t1, 0.f);
      acc2 += fmaxf(t2, 0.f);
      acc3 += fmaxf(t3, 0.f);
    }
  }

  // lanes 56..63 duplicated lane55's columns: zero before reduction (R2 lesson)
  if (lane >= 56) { acc0 = 0.f; acc1 = 0.f; acc2 = 0.f; acc3 = 0.f; }

  // wave reduce, cross-wave via LDS, one partial per block
#pragma unroll
  for (int off = 32; off > 0; off >>= 1) {
    acc0 += __shfl_down(acc0, off);
    acc1 += __shfl_down(acc1, off);
    acc2 += __shfl_down(acc2, off);
    acc3 += __shfl_down(acc3, off);
  }
  __shared__ float pl[4][4];
  if (lane == 0) {
    pl[wv][0] = acc0; pl[wv][1] = acc1; pl[wv][2] = acc2; pl[wv][3] = acc3;
  }
  __syncthreads();
  if (tid < 4) {
    float ssum = 0.f;
#pragma unroll
    for (int w = 0; w < 4; ++w) ssum += pl[w][tid];
    part[blk * 4 + tid] = ssum;
  }
}

// ---------------- Kernel 2: 4-qubit circuit + BatchNorm ----------------
template <int M>
__device__ __forceinline__ void ry_g(float (&sr)[16], float (&si)[16], float th) {
  float s, c;
  sincosf(0.5f * th, &s, &c);
#pragma unroll
  for (int i = 0; i < 16; ++i) {
    if (!(i & M)) {
      const int j = i | M;
      float r0 = sr[i], q0 = si[i], r1 = sr[j], q1 = si[j];
      sr[i] = c * r0 - s * r1;  si[i] = c * q0 - s * q1;
      sr[j] = s * r0 + c * r1;  si[j] = s * q0 + c * q1;
    }
  }
}

template <int M>
__device__ __forceinline__ void rz_g(float (&sr)[16], float (&si)[16], float th) {
  float s, c;
  sincosf(0.5f * th, &s, &c);
#pragma unroll
  for (int i = 0; i < 16; ++i) {
    float a = sr[i], q = si[i];
    if (i & M) { sr[i] = a * c - q * s;  si[i] = q * c + a * s; }
    else       { sr[i] = a * c + q * s;  si[i] = q * c - a * s; }
  }
}

template <int MC, int MT>
__device__ __forceinline__ void cnot_g(float (&sr)[16], float (&si)[16]) {
#pragma unroll
  for (int i = 0; i < 16; ++i) {
    if ((i & MC) && !(i & MT)) {
      const int j = i | MT;
      float tr = sr[i]; sr[i] = sr[j]; sr[j] = tr;
      float ti = si[i]; si[i] = si[j]; si[j] = ti;
    }
  }
}

__global__ __launch_bounds__(512) void circuit_bn_k(
    const float* __restrict__ part, const float* __restrict__ params,
    const float* __restrict__ gamma, const float* __restrict__ beta,
    float* __restrict__ out)
{
  const int b = threadIdx.x;  // batch element

  // gather 14 group partials per channel (float4 per group) -> features
  float4 fs = make_float4(0.f, 0.f, 0.f, 0.f);
#pragma unroll
  for (int s8 = 0; s8 < GROUPS; ++s8) {
    const float4 q = *reinterpret_cast<const float4*>(&part[(b * GROUPS + s8) * 4]);
    fs.x += q.x; fs.y += q.y; fs.z += q.z; fs.w += q.w;
  }
  float f[4] = { fs.x * (1.0f / NPIX), fs.y * (1.0f / NPIX),
                 fs.z * (1.0f / NPIX), fs.w * (1.0f / NPIX) };

  float sr[16], si[16];
#pragma unroll
  for (int i = 0; i < 16; ++i) { sr[i] = 0.f; si[i] = 0.f; }
  sr[0] = 1.f;

  ry_g<8>(sr, si, f[0]);
  ry_g<4>(sr, si, f[1]);
  ry_g<2>(sr, si, f[2]);
  ry_g<1>(sr, si, f[3]);

  for (int l = 0; l < NL; ++l) {
    const float* pp = params + l * 8;
    ry_g<8>(sr, si, pp[0]); rz_g<8>(sr, si, pp[1]);
    ry_g<4>(sr, si, pp[2]); rz_g<4>(sr, si, pp[3]);
    ry_g<2>(sr, si, pp[4]); rz_g<2>(sr, si, pp[5]);
    ry_g<1>(sr, si, pp[6]); rz_g<1>(sr, si, pp[7]);
    cnot_g<8, 4>(sr, si);
    cnot_g<4, 2>(sr, si);
    cnot_g<2, 1>(sr, si);
  }

  float p[16];
#pragma unroll
  for (int i = 0; i < 16; ++i) p[i] = sr[i] * sr[i] + si[i] * si[i];

  float ev[4];
#pragma unroll
  for (int w = 0; w < 4; ++w) {
    const int m = 8 >> w;
    float ssum = 0.f;
#pragma unroll
    for (int i = 0; i < 16; ++i) ssum += (i & m) ? -p[i] : p[i];
    ev[w] = ssum;
  }

  // BatchNorm over batch of 512 (biased variance) within this single block
  float sum[4], sq[4];
#pragma unroll
  for (int w = 0; w < 4; ++w) { sum[w] = ev[w]; sq[w] = ev[w] * ev[w]; }
#pragma unroll
  for (int off = 32; off > 0; off >>= 1) {
#pragma unroll
    for (int w = 0; w < 4; ++w) {
      sum[w] += __shfl_down(sum[w], off);
      sq[w]  += __shfl_down(sq[w],  off);
    }
  }
  __shared__ float psum[8][4], psq[8][4];
  __shared__ float mean_s[4], rstd_s[4];
  const int wave = b >> 6;
  const int lane = b & 63;
  if (lane == 0) {
#pragma unroll
    for (int w = 0; w < 4; ++w) { psum[wave][w] = sum[w]; psq[wave][w] = sq[w]; }
  }
  __syncthreads();
  if (b < 4) {
    float ssum = 0.f, q = 0.f;
#pragma unroll
    for (int wv = 0; wv < 8; ++wv) { ssum += psum[wv][b]; q += psq[wv][b]; }
    const float m = ssum * (1.0f / BATCH);
    const float v = q * (1.0f / BATCH) - m * m;
    mean_s[b] = m;
    rstd_s[b] = rsqrtf(v + EPSV);
  }
  __syncthreads();
#pragma unroll
  for (int w = 0; w < 4; ++w) {
    out[b * 4 + w] = gamma[w] * (ev[w] - mean_s[w]) * rstd_s[w] + beta[w];
  }
}

extern "C" void kernel_launch(void* const* d_in, const int* in_sizes, int n_in,
                              void* d_out, int out_size, void* d_ws, size_t ws_size,
                              hipStream_t stream) {
  const float* x      = (const float*)d_in[0];
  const float* cw     = (const float*)d_in[1];
  const float* params = (const float*)d_in[2];
  const float* gamma  = (const float*)d_in[3];
  const float* beta   = (const float*)d_in[4];
  float* out  = (float*)d_out;
  float* part = (float*)d_ws;   // 512*14*4 f32 partial sums (~114 KB)

  const int B = in_sizes[0] / NPIX;  // 512

  conv_pool_k<<<B * GROUPS, 256, 0, stream>>>(x, cw, part);
  circuit_bn_k<<<1, 512, 0, stream>>>(part, params, gamma, beta, out);
}

// Round 9
// 54.149 us; speedup vs baseline: 1.1406x; 1.0119x over previous
//
#include <hip/hip_runtime.h>
#include <math.h>

#define BATCH 512
#define HH 224
#define WW 224
#define NPIX (HH * WW)
#define NL 3
#define EPSV 1e-5f
#define GROUPS 8             // row-groups (blocks) per image; block covers 28 rows
#define ROWS_PER_WAVE 7      // wave covers 7 output rows

// ---------------- Kernel 1: conv3x3(1->4) + relu + partial sums ----------------
// Grid: 512 images * 8 groups. Block: 256 threads = 4 waves; wave owns 7 output
// rows x 224 cols; lane owns 4 cols (lanes 0..55 active, 56..63 clamped+zeroed).
// ALL 9 input rows are loaded up-front as unconditional float4 loads (row index
// clamped to [0,223]; OOB rows zeroed AFTER the load by an SGPR-uniform branch).
// One deep load batch per wave (9 in flight) amortizes the cold-HBM stall over
// ~2500 VALU cycles of compute. NOTE (R8 profiling): the harness's 411 MB
// workspace-poison fill between replays evicts x from L3, so conv always pays
// HBM latency — more compute per load batch is the lever, not cache locality.
// R4: direct k-indexing (no ring off-by-one). R5: no min-waves clause (spill).
// R6: guarded per-iter loads get sunk -> load all upfront. R7: no LDS staging.
__global__ __launch_bounds__(256) void conv_pool_k(
    const float* __restrict__ x, const float* __restrict__ cw,
    float* __restrict__ part)
{
  const int blk = blockIdx.x;
  const int b = blk >> 3;          // image
  const int g = blk & 7;           // row-group
  const int tid = threadIdx.x;
  const int wv = __builtin_amdgcn_readfirstlane(tid >> 6);  // SGPR wave id
  const int lane = tid & 63;
  const int r0 = g * 28 + wv * ROWS_PER_WAVE;   // first output row (SGPR)
  const int colc = (lane < 56 ? lane : 55) * 4; // clamped col
  const float* __restrict__ img = x + (size_t)b * NPIX;

  // 4x9 weights: uniform address -> scalar loads -> SGPRs
  float K[4][9];
#pragma unroll
  for (int o = 0; o < 4; ++o)
#pragma unroll
    for (int k = 0; k < 9; ++k) K[o][k] = cw[o * 9 + k];

  // ---- load ALL 9 input rows up front (unconditional, clamped addresses) ----
  float4 v[9];
#pragma unroll
  for (int k = 0; k < 9; ++k) {
    int rr = r0 - 1 + k;                       // wave-uniform
    int rc = rr < 0 ? 0 : (rr > HH - 1 ? HH - 1 : rr);
    v[k] = *reinterpret_cast<const float4*>(img + (size_t)rc * WW + colc);
  }
  // zero logically-OOB rows (SGPR-uniform branch; only first/last group hit)
#pragma unroll
  for (int k = 0; k < 9; ++k) {
    int rr = r0 - 1 + k;
    if (rr < 0 || rr > HH - 1) v[k] = make_float4(0.f, 0.f, 0.f, 0.f);
  }

  // expand float4 into [left, x, y, z, w, right] via cross-lane shfl
  auto expand = [&](const float4& t, float (&R)[6]) {
    float lft = __shfl_up(t.w, 1);
    R[0] = (lane == 0) ? 0.f : lft;       // image left edge
    float rgt = __shfl_down(t.x, 1);
    R[5] = (lane == 55) ? 0.f : rgt;      // image right edge (lane56 dups lane55)
    R[1] = t.x; R[2] = t.y; R[3] = t.z; R[4] = t.w;
  };

  float E[3][6];
  expand(v[0], E[0]);
  expand(v[1], E[1]);

  float acc0 = 0.f, acc1 = 0.f, acc2 = 0.f, acc3 = 0.f;

#pragma unroll
  for (int i = 0; i < ROWS_PER_WAVE; ++i) {   // 7 output rows
    float (&A)[6] = E[i % 3];
    float (&B)[6] = E[(i + 1) % 3];
    float (&C)[6] = E[(i + 2) % 3];
    expand(v[i + 2], C);

#pragma unroll
    for (int p = 0; p < 4; ++p) {
      const float a0 = A[p], a1 = A[p + 1], a2 = A[p + 2];
      const float b0 = B[p], b1 = B[p + 1], b2 = B[p + 2];
      const float c0 = C[p], c1 = C[p + 1], c2 = C[p + 2];
      float t0 = fmaf(a0, K[0][0], fmaf(a1, K[0][1], fmaf(a2, K[0][2],
                 fmaf(b0, K[0][3], fmaf(b1, K[0][4], fmaf(b2, K[0][5],
                 fmaf(c0, K[0][6], fmaf(c1, K[0][7], c2 * K[0][8]))))))));
      float t1 = fmaf(a0, K[1][0], fmaf(a1, K[1][1], fmaf(a2, K[1][2],
                 fmaf(b0, K[1][3], fmaf(b1, K[1][4], fmaf(b2, K[1][5],
                 fmaf(c0, K[1][6], fmaf(c1, K[1][7], c2 * K[1][8]))))))));
      float t2 = fmaf(a0, K[2][0], fmaf(a1, K[2][1], fmaf(a2, K[2][2],
                 fmaf(b0, K[2][3], fmaf(b1, K[2][4], fmaf(b2, K[2][5],
                 fmaf(c0, K[2][6], fmaf(c1, K[2][7], c2 * K[2][8]))))))));
      float t3 = fmaf(a0, K[3][0], fmaf(a1, K[3][1], fmaf(a2, K[3][2],
                 fmaf(b0, K[3][3], fmaf(b1, K[3][4], fmaf(b2, K[3][5],
                 fmaf(c0, K[3][6], fmaf(c1, K[3][7], c2 * K[3][8]))))))));
      acc0 += fmaxf(t0, 0.f);
      acc1 += fmaxf(t1, 0.f);
      acc2 += fmaxf(t2, 0.f);
      acc3 += fmaxf(t3, 0.f);
    }
  }

  // lanes 56..63 duplicated lane55's columns: zero before reduction (R2 lesson)
  if (lane >= 56) { acc0 = 0.f; acc1 = 0.f; acc2 = 0.f; acc3 = 0.f; }

  // wave reduce, cross-wave via LDS, one partial per block
#pragma unroll
  for (int off = 32; off > 0; off >>= 1) {
    acc0 += __shfl_down(acc0, off);
    acc1 += __shfl_down(acc1, off);
    acc2 += __shfl_down(acc2, off);
    acc3 += __shfl_down(acc3, off);
  }
  __shared__ float pl[4][4];
  if (lane == 0) {
    pl[wv][0] = acc0; pl[wv][1] = acc1; pl[wv][2] = acc2; pl[wv][3] = acc3;
  }
  __syncthreads();
  if (tid < 4) {
    float ssum = 0.f;
#pragma unroll
    for (int w = 0; w < 4; ++w) ssum += pl[w][tid];
    part[blk * 4 + tid] = ssum;
  }
}

// ---------------- Kernel 2: 4-qubit circuit + BatchNorm ----------------
template <int M>
__device__ __forceinline__ void ry_g(float (&sr)[16], float (&si)[16], float th) {
  float s, c;
  sincosf(0.5f * th, &s, &c);
#pragma unroll
  for (int i = 0; i < 16; ++i) {
    if (!(i & M)) {
      const int j = i | M;
      float r0 = sr[i], q0 = si[i], r1 = sr[j], q1 = si[j];
      sr[i] = c * r0 - s * r1;  si[i] = c * q0 - s * q1;
      sr[j] = s * r0 + c * r1;  si[j] = s * q0 + c * q1;
    }
  }
}

template <int M>
__device__ __forceinline__ void rz_g(float (&sr)[16], float (&si)[16], float th) {
  float s, c;
  sincosf(0.5f * th, &s, &c);
#pragma unroll
  for (int i = 0; i < 16; ++i) {
    float a = sr[i], q = si[i];
    if (i & M) { sr[i] = a * c - q * s;  si[i] = q * c + a * s; }
    else       { sr[i] = a * c + q * s;  si[i] = q * c - a * s; }
  }
}

template <int MC, int MT>
__device__ __forceinline__ void cnot_g(float (&sr)[16], float (&si)[16]) {
#pragma unroll
  for (int i = 0; i < 16; ++i) {
    if ((i & MC) && !(i & MT)) {
      const int j = i | MT;
      float tr = sr[i]; sr[i] = sr[j]; sr[j] = tr;
      float ti = si[i]; si[i] = si[j]; si[j] = ti;
    }
  }
}

__global__ __launch_bounds__(512) void circuit_bn_k(
    const float* __restrict__ part, const float* __restrict__ params,
    const float* __restrict__ gamma, const float* __restrict__ beta,
    float* __restrict__ out)
{
  const int b = threadIdx.x;  // batch element

  // gather 8 group partials per channel (float4 per group) -> features
  float4 fs = make_float4(0.f, 0.f, 0.f, 0.f);
#pragma unroll
  for (int s8 = 0; s8 < GROUPS; ++s8) {
    const float4 q = *reinterpret_cast<const float4*>(&part[(b * GROUPS + s8) * 4]);
    fs.x += q.x; fs.y += q.y; fs.z += q.z; fs.w += q.w;
  }
  float f[4] = { fs.x * (1.0f / NPIX), fs.y * (1.0f / NPIX),
                 fs.z * (1.0f / NPIX), fs.w * (1.0f / NPIX) };

  float sr[16], si[16];
#pragma unroll
  for (int i = 0; i < 16; ++i) { sr[i] = 0.f; si[i] = 0.f; }
  sr[0] = 1.f;

  ry_g<8>(sr, si, f[0]);
  ry_g<4>(sr, si, f[1]);
  ry_g<2>(sr, si, f[2]);
  ry_g<1>(sr, si, f[3]);

  for (int l = 0; l < NL; ++l) {
    const float* pp = params + l * 8;
    ry_g<8>(sr, si, pp[0]); rz_g<8>(sr, si, pp[1]);
    ry_g<4>(sr, si, pp[2]); rz_g<4>(sr, si, pp[3]);
    ry_g<2>(sr, si, pp[4]); rz_g<2>(sr, si, pp[5]);
    ry_g<1>(sr, si, pp[6]); rz_g<1>(sr, si, pp[7]);
    cnot_g<8, 4>(sr, si);
    cnot_g<4, 2>(sr, si);
    cnot_g<2, 1>(sr, si);
  }

  float p[16];
#pragma unroll
  for (int i = 0; i < 16; ++i) p[i] = sr[i] * sr[i] + si[i] * si[i];

  float ev[4];
#pragma unroll
  for (int w = 0; w < 4; ++w) {
    const int m = 8 >> w;
    float ssum = 0.f;
#pragma unroll
    for (int i = 0; i < 16; ++i) ssum += (i & m) ? -p[i] : p[i];
    ev[w] = ssum;
  }

  // BatchNorm over batch of 512 (biased variance) within this single block
  float sum[4], sq[4];
#pragma unroll
  for (int w = 0; w < 4; ++w) { sum[w] = ev[w]; sq[w] = ev[w] * ev[w]; }
#pragma unroll
  for (int off = 32; off > 0; off >>= 1) {
#pragma unroll
    for (int w = 0; w < 4; ++w) {
      sum[w] += __shfl_down(sum[w], off);
      sq[w]  += __shfl_down(sq[w],  off);
    }
  }
  __shared__ float psum[8][4], psq[8][4];
  __shared__ float mean_s[4], rstd_s[4];
  const int wave = b >> 6;
  const int lane = b & 63;
  if (lane == 0) {
#pragma unroll
    for (int w = 0; w < 4; ++w) { psum[wave][w] = sum[w]; psq[wave][w] = sq[w]; }
  }
  __syncthreads();
  if (b < 4) {
    float ssum = 0.f, q = 0.f;
#pragma unroll
    for (int wv = 0; wv < 8; ++wv) { ssum += psum[wv][b]; q += psq[wv][b]; }
    const float m = ssum * (1.0f / BATCH);
    const float v = q * (1.0f / BATCH) - m * m;
    mean_s[b] = m;
    rstd_s[b] = rsqrtf(v + EPSV);
  }
  __syncthreads();
#pragma unroll
  for (int w = 0; w < 4; ++w) {
    out[b * 4 + w] = gamma[w] * (ev[w] - mean_s[w]) * rstd_s[w] + beta[w];
  }
}

extern "C" void kernel_launch(void* const* d_in, const int* in_sizes, int n_in,
                              void* d_out, int out_size, void* d_ws, size_t ws_size,
                              hipStream_t stream) {
  const float* x      = (const float*)d_in[0];
  const float* cw     = (const float*)d_in[1];
  const float* params = (const float*)d_in[2];
  const float* gamma  = (const float*)d_in[3];
  const float* beta   = (const float*)d_in[4];
  float* out  = (float*)d_out;
  float* part = (float*)d_ws;   // 512*8*4 f32 partial sums

  const int B = in_sizes[0] / NPIX;  // 512

  conv_pool_k<<<B * GROUPS, 256, 0, stream>>>(x, cw, part);
  circuit_bn_k<<<1, 512, 0, stream>>>(part, params, gamma, beta, out);
}